// Round 3
// baseline (399.313 us; speedup 1.0000x reference)
//
#include <hip/hip_runtime.h>
#include <math.h>

#define HEADS 4
#define KB 8
#define Bsz 8
#define Nn 10000
#define Hh 512
#define HD 128   // head dim = Hh/HEADS
#define NPART 128

// ws layout (float offsets)
#define XS_OFF   0         // (unused now)
#define KSUM_OFF 4096      // [B][H]        4096
#define VSUM_OFF 8192      // [B][H]        4096
#define WQE_OFF  12288     // [B][4][H]    16384
#define WOE_OFF  28672     // [B][4][H]    16384
#define ESUM_OFF 45056     // [4][8]          32
#define FSUM_OFF 45088     // [4][8]          32
#define BQ_OFF   45120     // [B][4]          32
#define BD_OFF   45152     // [4][8]          32

// large partials live in d_out's head region (overwritten later by k_main):
//   xpart  [NPART][B][Hh] = 524288 floats
//   efpart [2][4][8][8]   =    512 floats   @ +524288

typedef float vf4 __attribute__((ext_vector_type(4)));
__device__ __forceinline__ void nt_store4(float* p, const float4& v) {
    vf4 tmp;
    tmp[0] = v.x; tmp[1] = v.y; tmp[2] = v.z; tmp[3] = v.w;
    __builtin_nontemporal_store(tmp, (vf4*)p);
}

// ---------------- K1: partial sums (atomic-free) ----------------
// blocks 0..1023: colsum partials of x. blocks 1024..1087: E/F partials.
__global__ __launch_bounds__(256) void k_part(const float* __restrict__ x,
                                              const float* __restrict__ E,
                                              const float* __restrict__ Fp,
                                              float* __restrict__ xpart,
                                              float* __restrict__ efpart) {
    int blk = blockIdx.x;
    int t = threadIdx.x;
    if (blk < NPART * Bsz) {
        int p = blk >> 3, b = blk & 7;
        const int CH = (Nn + NPART - 1) / NPART;  // 79
        int n0 = p * CH, n1 = min(n0 + CH, Nn);
        int c = t * 2;
        float a0 = 0.f, a1 = 0.f;
        const float* base = x + (size_t)b * Nn * Hh + c;
#pragma unroll 8
        for (int n = n0; n < n1; ++n) {
            float2 v = *(const float2*)(base + (size_t)n * Hh);
            a0 += v.x; a1 += v.y;
        }
        float* o = xpart + (size_t)(p * Bsz + b) * Hh;
        o[c] = a0; o[c + 1] = a1;
    } else {
        int idx = blk - NPART * Bsz;  // 0..63
        int src = idx >> 5, h = (idx >> 3) & 3, ch = idx & 7;
        const float* S = src ? Fp : E;
        const int CHE = Nn / 8;  // 1250
        int n0 = ch * CHE, n1 = n0 + CHE;
        int kk = t & 7, part = t >> 3;  // 32 parts
        float acc = 0.f;
        const float* base = S + (size_t)h * Nn * KB;
#pragma unroll 4
        for (int n = n0 + part; n < n1; n += 32) acc += base[n * KB + kk];
        __shared__ float sd[256];
        sd[t] = acc;
        __syncthreads();
        for (int s = 128; s >= 8; s >>= 1) {
            if (t < s) sd[t] += sd[t + s];
            __syncthreads();
        }
        if (t < 8) efpart[idx * 8 + t] = sd[t];
    }
}

// ---------------- K2: gemv (self-reduces xs from xpart) + EF reduce ----------------
// blocks 0..15: m=blk&1 (Wk/Wv), rg=blk>>1. block 16: esum/fsum reduce.
__global__ __launch_bounds__(256) void k_gemv2(const float* __restrict__ Wk,
                                               const float* __restrict__ bk,
                                               const float* __restrict__ Wv,
                                               const float* __restrict__ bv,
                                               const float* __restrict__ xpart,
                                               const float* __restrict__ efpart,
                                               float* __restrict__ ksum,
                                               float* __restrict__ vsum,
                                               float* __restrict__ esum,
                                               float* __restrict__ fsum) {
    int blk = blockIdx.x;
    int t = threadIdx.x;
    if (blk >= 16) {
        if (t < 64) {
            int src = t >> 5, rem = t & 31;  // rem = h*8+kk
            float a = 0.f;
#pragma unroll
            for (int ch = 0; ch < 8; ++ch)
                a += efpart[((src * 4 + (rem >> 3)) * 8 + ch) * 8 + (rem & 7)];
            if (src == 0) esum[rem] = a; else fsum[rem] = a;
        }
        return;
    }
    int m = blk & 1, rg = blk >> 1;
    const float* W = m ? Wv : Wk;
    const float* bias = m ? bv : bk;
    float* out = m ? vsum : ksum;
    __shared__ float xsL[Bsz * Hh];
    // self-reduce xs from xpart (16 independent accumulators for MLP)
    {
        float acc[16];
#pragma unroll
        for (int j = 0; j < 16; ++j) acc[j] = 0.f;
        for (int p = 0; p < NPART; ++p) {
            const float* row = xpart + (size_t)p * (Bsz * Hh);
#pragma unroll
            for (int j = 0; j < 16; ++j) acc[j] += row[t + 256 * j];
        }
#pragma unroll
        for (int j = 0; j < 16; ++j) xsL[t + 256 * j] = acc[j];
    }
    __syncthreads();
    int wid = t >> 6, lane = t & 63;
    for (int i = 0; i < 16; ++i) {
        int r = rg * 64 + wid + 4 * i;
        float4 wa = *(const float4*)(W + (size_t)r * Hh + lane * 4);
        float4 wb = *(const float4*)(W + (size_t)r * Hh + 256 + lane * 4);
        float p[Bsz];
#pragma unroll
        for (int b = 0; b < Bsz; ++b) {
            const float4 x0 = *(const float4*)(&xsL[b * Hh + lane * 4]);
            const float4 x1 = *(const float4*)(&xsL[b * Hh + 256 + lane * 4]);
            p[b] = wa.x * x0.x + wa.y * x0.y + wa.z * x0.z + wa.w * x0.w +
                   wb.x * x1.x + wb.y * x1.y + wb.z * x1.z + wb.w * x1.w;
        }
#pragma unroll
        for (int off = 32; off >= 1; off >>= 1)
#pragma unroll
            for (int b = 0; b < Bsz; ++b) p[b] += __shfl_xor(p[b], off, 64);
        if (lane == 0) {
            float bb = (float)Nn * bias[r];
#pragma unroll
            for (int b = 0; b < Bsz; ++b) out[b * Hh + r] = p[b] + bb;
        }
    }
}

// ---------------- K3: wq_eff / wo_eff + (block 64) bias_q, bias_diag, reg ----------------
__global__ __launch_bounds__(256) void k_eff2(const float* __restrict__ Wq,
                                              const float* __restrict__ Wo,
                                              const float* __restrict__ ksum,
                                              const float* __restrict__ vsum,
                                              float* __restrict__ wqe,
                                              float* __restrict__ woe,
                                              const float* __restrict__ bq,
                                              const float* __restrict__ gbu,
                                              const float* __restrict__ gbv,
                                              const float* __restrict__ log_reg,
                                              float* __restrict__ bias_q,
                                              float* __restrict__ bias_diag,
                                              float* __restrict__ reg_out) {
    int blk = blockIdx.x;
    int t = threadIdx.x;
    __shared__ float sL[256];
    if (blk < 64) {
        int b = blk >> 3, rem = blk & 7, h = rem >> 1, m = rem & 1;
        const float* s = (m ? vsum : ksum) + b * Hh + h * HD;
        float* out = (m ? woe : wqe) + (size_t)(b * HEADS + h) * Hh;
        if (t < HD) sL[t] = s[t];
        __syncthreads();
        float a0 = 0.f, a1 = 0.f;
        if (m == 0) {
            const float* Wb = Wq + (size_t)h * HD * Hh;
#pragma unroll 4
            for (int d = 0; d < HD; ++d) {
                float sv = sL[d];
                a0 += Wb[(size_t)d * Hh + t] * sv;
                a1 += Wb[(size_t)d * Hh + t + 256] * sv;
            }
        } else {
            const float* W0 = Wo + (size_t)t * Hh + h * HD;
            const float* W1 = Wo + (size_t)(t + 256) * Hh + h * HD;
            for (int d = 0; d < HD; d += 4) {
                a0 += W0[d] * sL[d] + W0[d + 1] * sL[d + 1] + W0[d + 2] * sL[d + 2] + W0[d + 3] * sL[d + 3];
                a1 += W1[d] * sL[d] + W1[d + 1] * sL[d + 1] + W1[d + 2] * sL[d + 2] + W1[d + 3] * sL[d + 3];
            }
        }
        out[t] = a0;
        out[t + 256] = a1;
    } else {
        int h = t >> 6, i = (t >> 3) & 7, j = t & 7;
        float gb = 0.f;
#pragma unroll
        for (int l = 0; l < 8; ++l) gb += gbu[h * 64 + i * 8 + l] * gbv[h * 64 + l * 8 + j];
        if (i == j) bias_diag[h * 8 + i] = gb;
        sL[t] = fabsf(gb);
        __syncthreads();
        for (int s = 128; s >= 1; s >>= 1) {
            if (t < s) sL[t] += sL[t + s];
            __syncthreads();
        }
        if (t == 0) {
            float gbmean = sL[0] / 256.f;
            reg_out[0] = expf(log_reg[0]) * (0.125f + gbmean * 0.1f);
        }
        if (t < 32) {
            int b = t >> 2, hh = t & 3;
            float a = 0.f;
            for (int d = 0; d < HD; ++d) a += bq[hh * HD + d] * ksum[b * Hh + hh * HD + d];
            bias_q[t] = a;  // [b][h]
        }
    }
}

// ---------------- K4: main pass ----------------
// grid (250, B), block 256 = 4 waves; wave-per-row, 10 rows/wave.
__global__ __launch_bounds__(256) void k_main(const float* __restrict__ x,
                                              const float* __restrict__ bo,
                                              const float* __restrict__ wqe,
                                              const float* __restrict__ woe,
                                              const float* __restrict__ esum,
                                              const float* __restrict__ fsum,
                                              const float* __restrict__ bias_q,
                                              const float* __restrict__ bias_diag,
                                              float* __restrict__ out) {
    int b = blockIdx.y;
    __shared__ float woL[HEADS * Hh];  // 8 KB
    int t = threadIdx.x;
    const float* woe_b = woe + (size_t)b * HEADS * Hh;
    for (int i = t; i < HEADS * Hh; i += 256) woL[i] = woe_b[i];

    int wid = t >> 6, lane = t & 63;
    const float* wqe_b = wqe + (size_t)b * HEADS * Hh;
    float4 wqa[HEADS], wqb[HEADS];
#pragma unroll
    for (int h = 0; h < HEADS; ++h) {
        wqa[h] = *(const float4*)(wqe_b + h * Hh + lane * 4);
        wqb[h] = *(const float4*)(wqe_b + h * Hh + 256 + lane * 4);
    }
    float4 boa = *(const float4*)(bo + lane * 4);
    float4 bob = *(const float4*)(bo + 256 + lane * 4);
    // softmax lane mapping: j = lane&31 -> head g = j>>3, slot kk = j&7
    int j = lane & 31, g = j >> 3;
    float eV = esum[j];
    float fV = fsum[j];
    float bdV = bias_diag[j];
    float bqV = bias_q[b * HEADS + g];
    __syncthreads();

    const float inv_sqrt_hd = 0.08838834764831843f;  // 1/sqrt(128)
    int wavesPerB = gridDim.x * 4;

    for (int n = blockIdx.x * 4 + wid; n < Nn; n += wavesPerB) {
        const float* xr = x + ((size_t)b * Nn + n) * Hh;
        float4 xa = *(const float4*)(xr + lane * 4);
        float4 xb = *(const float4*)(xr + 256 + lane * 4);
        float p[HEADS];
#pragma unroll
        for (int h = 0; h < HEADS; ++h) {
            p[h] = xa.x * wqa[h].x + xa.y * wqa[h].y + xa.z * wqa[h].z + xa.w * wqa[h].w +
                   xb.x * wqb[h].x + xb.y * wqb[h].y + xb.z * wqb[h].z + xb.w * wqb[h].w;
        }
#pragma unroll
        for (int off = 32; off >= 1; off >>= 1)
#pragma unroll
            for (int h = 0; h < HEADS; ++h) p[h] += __shfl_xor(p[h], off, 64);

        float sq = (p[g] + bqV) * inv_sqrt_hd;
        float sc = eV * sq + bdV;
        float m = sc;
        m = fmaxf(m, __shfl_xor(m, 1, 64));
        m = fmaxf(m, __shfl_xor(m, 2, 64));
        m = fmaxf(m, __shfl_xor(m, 4, 64));
        float e = __expf(sc - m);
        float se = e, sw = e * fV;
        se += __shfl_xor(se, 1, 64); sw += __shfl_xor(sw, 1, 64);
        se += __shfl_xor(se, 2, 64); sw += __shfl_xor(sw, 2, 64);
        se += __shfl_xor(se, 4, 64); sw += __shfl_xor(sw, 4, 64);
        float wv = sw / se;
        float w0 = __shfl(wv, 0, 64);
        float w1 = __shfl(wv, 8, 64);
        float w2 = __shfl(wv, 16, 64);
        float w3 = __shfl(wv, 24, 64);

        float4 oa = boa, ob = bob;
        {
            float4 wa = *(const float4*)(&woL[0 * Hh + lane * 4]);
            float4 wb = *(const float4*)(&woL[0 * Hh + 256 + lane * 4]);
            oa.x += w0 * wa.x; oa.y += w0 * wa.y; oa.z += w0 * wa.z; oa.w += w0 * wa.w;
            ob.x += w0 * wb.x; ob.y += w0 * wb.y; ob.z += w0 * wb.z; ob.w += w0 * wb.w;
        }
        {
            float4 wa = *(const float4*)(&woL[1 * Hh + lane * 4]);
            float4 wb = *(const float4*)(&woL[1 * Hh + 256 + lane * 4]);
            oa.x += w1 * wa.x; oa.y += w1 * wa.y; oa.z += w1 * wa.z; oa.w += w1 * wa.w;
            ob.x += w1 * wb.x; ob.y += w1 * wb.y; ob.z += w1 * wb.z; ob.w += w1 * wb.w;
        }
        {
            float4 wa = *(const float4*)(&woL[2 * Hh + lane * 4]);
            float4 wb = *(const float4*)(&woL[2 * Hh + 256 + lane * 4]);
            oa.x += w2 * wa.x; oa.y += w2 * wa.y; oa.z += w2 * wa.z; oa.w += w2 * wa.w;
            ob.x += w2 * wb.x; ob.y += w2 * wb.y; ob.z += w2 * wb.z; ob.w += w2 * wb.w;
        }
        {
            float4 wa = *(const float4*)(&woL[3 * Hh + lane * 4]);
            float4 wb = *(const float4*)(&woL[3 * Hh + 256 + lane * 4]);
            oa.x += w3 * wa.x; oa.y += w3 * wa.y; oa.z += w3 * wa.z; oa.w += w3 * wa.w;
            ob.x += w3 * wb.x; ob.y += w3 * wb.y; ob.z += w3 * wb.z; ob.w += w3 * wb.w;
        }
        float* orow = out + ((size_t)b * Nn + n) * Hh;
        nt_store4(orow + lane * 4, oa);
        nt_store4(orow + 256 + lane * 4, ob);
    }
}

extern "C" void kernel_launch(void* const* d_in, const int* in_sizes, int n_in,
                              void* d_out, int out_size, void* d_ws, size_t ws_size,
                              hipStream_t stream) {
    const float* x       = (const float*)d_in[0];
    const float* Wq      = (const float*)d_in[1];
    const float* bq      = (const float*)d_in[2];
    const float* Wk      = (const float*)d_in[3];
    const float* bk      = (const float*)d_in[4];
    const float* Wv      = (const float*)d_in[5];
    const float* bv      = (const float*)d_in[6];
    const float* E       = (const float*)d_in[7];
    const float* Fp      = (const float*)d_in[8];
    const float* gbu     = (const float*)d_in[9];
    const float* gbv     = (const float*)d_in[10];
    const float* Wo      = (const float*)d_in[11];
    const float* bo      = (const float*)d_in[12];
    const float* log_reg = (const float*)d_in[13];

    float* out = (float*)d_out;
    float* ws = (float*)d_ws;
    float* ksum = ws + KSUM_OFF;
    float* vsum = ws + VSUM_OFF;
    float* wqe  = ws + WQE_OFF;
    float* woe  = ws + WOE_OFF;
    float* esum = ws + ESUM_OFF;
    float* fsum = ws + FSUM_OFF;
    float* bias_q = ws + BQ_OFF;
    float* bias_diag = ws + BD_OFF;
    float* reg_out = out + (size_t)Bsz * Nn * Hh;

    // stage partials in d_out's head region (overwritten by k_main afterwards)
    float* xpart  = out;
    float* efpart = out + (size_t)NPART * Bsz * Hh;

    k_part<<<NPART * Bsz + 64, 256, 0, stream>>>(x, E, Fp, xpart, efpart);
    k_gemv2<<<17, 256, 0, stream>>>(Wk, bk, Wv, bv, xpart, efpart, ksum, vsum, esum, fsum);
    k_eff2<<<65, 256, 0, stream>>>(Wq, Wo, ksum, vsum, wqe, woe,
                                   bq, gbu, gbv, log_reg, bias_q, bias_diag, reg_out);
    k_main<<<dim3(250, Bsz), 256, 0, stream>>>(x, bo, wqe, woe, esum, fsum, bias_q, bias_diag, out);
}

// Round 4
// 382.167 us; speedup vs baseline: 1.0449x; 1.0449x over previous
//
#include <hip/hip_runtime.h>
#include <math.h>

#define HEADS 4
#define KB 8
#define Bsz 8
#define Nn 10000
#define Hh 512
#define HD 128   // head dim = Hh/HEADS
#define NPART 64

// ws layout (float offsets)
#define KSUM_OFF 4096      // [B][H]        4096
#define VSUM_OFF 8192      // [B][H]        4096
#define WQE_OFF  12288     // [B][4][H]    16384
#define WOE_OFF  28672     // [B][4][H]    16384
#define ESUM_OFF 45056     // [4][8]          32
#define FSUM_OFF 45088     // [4][8]          32
#define BQ_OFF   45120     // [B][4]          32
#define BD_OFF   45152     // [4][8]          32

// large partials live in d_out's head region (overwritten later by k_main):
//   xpart  [NPART][B][Hh] = 262144 floats
//   efpart [2][4][8][8]   =    512 floats   @ +262144

// ---------------- K1: partial sums (atomic-free) ----------------
__global__ __launch_bounds__(256) void k_part(const float* __restrict__ x,
                                              const float* __restrict__ E,
                                              const float* __restrict__ Fp,
                                              float* __restrict__ xpart,
                                              float* __restrict__ efpart) {
    int blk = blockIdx.x;
    int t = threadIdx.x;
    if (blk < NPART * Bsz) {
        int p = blk >> 3, b = blk & 7;
        const int CH = (Nn + NPART - 1) / NPART;  // 157
        int n0 = p * CH, n1 = min(n0 + CH, Nn);
        int c = t * 2;
        float a0 = 0.f, a1 = 0.f;
        const float* base = x + (size_t)b * Nn * Hh + c;
#pragma unroll 4
        for (int n = n0; n < n1; ++n) {
            float2 v = *(const float2*)(base + (size_t)n * Hh);
            a0 += v.x; a1 += v.y;
        }
        float* o = xpart + (size_t)(p * Bsz + b) * Hh;
        o[c] = a0; o[c + 1] = a1;
    } else {
        int idx = blk - NPART * Bsz;  // 0..63
        int src = idx >> 5, h = (idx >> 3) & 3, ch = idx & 7;
        const float* S = src ? Fp : E;
        const int CHE = Nn / 8;  // 1250
        int n0 = ch * CHE, n1 = n0 + CHE;
        int kk = t & 7, part = t >> 3;  // 32 parts
        float acc = 0.f;
        const float* base = S + (size_t)h * Nn * KB;
#pragma unroll 4
        for (int n = n0 + part; n < n1; n += 32) acc += base[n * KB + kk];
        __shared__ float sd[256];
        sd[t] = acc;
        __syncthreads();
        for (int s = 128; s >= 8; s >>= 1) {
            if (t < s) sd[t] += sd[t + s];
            __syncthreads();
        }
        if (t < 8) efpart[idx * 8 + t] = sd[t];
    }
}

// ---------------- K2: reduce partials ----------------
__global__ __launch_bounds__(256) void k_reduce(const float* __restrict__ xpart,
                                                const float* __restrict__ efpart,
                                                float* __restrict__ xs,
                                                float* __restrict__ esum,
                                                float* __restrict__ fsum) {
    int blk = blockIdx.x, t = threadIdx.x;
    if (blk < 16) {
        int o = blk * 256 + t;  // b*512 + c
        float a = 0.f;
#pragma unroll 8
        for (int p = 0; p < NPART; ++p) a += xpart[(size_t)p * (Bsz * Hh) + o];
        xs[o] = a;
    } else if (t < 64) {
        int src = t >> 5, rem = t & 31;  // rem = h*8+kk
        float a = 0.f;
#pragma unroll
        for (int ch = 0; ch < 8; ++ch)
            a += efpart[((src * 4 + (rem >> 3)) * 8 + ch) * 8 + (rem & 7)];
        if (src == 0) esum[rem] = a; else fsum[rem] = a;
    }
}

// ---------------- K3: ksum[b,r] = sum_c Wk[r,c]*xs[b,c] + N*bk[r] ----------------
__global__ __launch_bounds__(256) void k_gemv(const float* __restrict__ Wk,
                                              const float* __restrict__ bk,
                                              const float* __restrict__ Wv,
                                              const float* __restrict__ bv,
                                              const float* __restrict__ xs,
                                              float* __restrict__ ksum,
                                              float* __restrict__ vsum) {
    int m = blockIdx.x;
    int rg = blockIdx.y;
    const float* W = m ? Wv : Wk;
    const float* bias = m ? bv : bk;
    float* out = m ? vsum : ksum;
    __shared__ float xsL[Bsz * Hh];
    int t = threadIdx.x;
    for (int i = t; i < Bsz * Hh; i += 256) xsL[i] = xs[i];
    __syncthreads();
    int wid = t >> 6, lane = t & 63;
    for (int i = 0; i < 16; ++i) {
        int r = rg * 64 + wid + 4 * i;
        float4 wa = *(const float4*)(W + (size_t)r * Hh + lane * 4);
        float4 wb = *(const float4*)(W + (size_t)r * Hh + 256 + lane * 4);
        float p[Bsz];
#pragma unroll
        for (int b = 0; b < Bsz; ++b) {
            const float4 x0 = *(const float4*)(&xsL[b * Hh + lane * 4]);
            const float4 x1 = *(const float4*)(&xsL[b * Hh + 256 + lane * 4]);
            p[b] = wa.x * x0.x + wa.y * x0.y + wa.z * x0.z + wa.w * x0.w +
                   wb.x * x1.x + wb.y * x1.y + wb.z * x1.z + wb.w * x1.w;
        }
#pragma unroll
        for (int off = 32; off >= 1; off >>= 1)
#pragma unroll
            for (int b = 0; b < Bsz; ++b) p[b] += __shfl_xor(p[b], off, 64);
        if (lane == 0) {
            float bb = (float)Nn * bias[r];
#pragma unroll
            for (int b = 0; b < Bsz; ++b) out[b * Hh + r] = p[b] + bb;
        }
    }
}

// ---------------- K4: wq_eff / wo_eff + (block 64) bias_q, bias_diag, reg ----------------
__global__ __launch_bounds__(256) void k_eff2(const float* __restrict__ Wq,
                                              const float* __restrict__ Wo,
                                              const float* __restrict__ ksum,
                                              const float* __restrict__ vsum,
                                              float* __restrict__ wqe,
                                              float* __restrict__ woe,
                                              const float* __restrict__ bq,
                                              const float* __restrict__ gbu,
                                              const float* __restrict__ gbv,
                                              const float* __restrict__ log_reg,
                                              float* __restrict__ bias_q,
                                              float* __restrict__ bias_diag,
                                              float* __restrict__ reg_out) {
    int blk = blockIdx.x;
    int t = threadIdx.x;
    __shared__ float sL[256];
    if (blk < 64) {
        int b = blk >> 3, rem = blk & 7, h = rem >> 1, m = rem & 1;
        const float* s = (m ? vsum : ksum) + b * Hh + h * HD;
        float* out = (m ? woe : wqe) + (size_t)(b * HEADS + h) * Hh;
        if (t < HD) sL[t] = s[t];
        __syncthreads();
        float a0 = 0.f, a1 = 0.f;
        if (m == 0) {
            const float* Wb = Wq + (size_t)h * HD * Hh;
#pragma unroll 4
            for (int d = 0; d < HD; ++d) {
                float sv = sL[d];
                a0 += Wb[(size_t)d * Hh + t] * sv;
                a1 += Wb[(size_t)d * Hh + t + 256] * sv;
            }
        } else {
            const float* W0 = Wo + (size_t)t * Hh + h * HD;
            const float* W1 = Wo + (size_t)(t + 256) * Hh + h * HD;
            for (int d = 0; d < HD; d += 4) {
                a0 += W0[d] * sL[d] + W0[d + 1] * sL[d + 1] + W0[d + 2] * sL[d + 2] + W0[d + 3] * sL[d + 3];
                a1 += W1[d] * sL[d] + W1[d + 1] * sL[d + 1] + W1[d + 2] * sL[d + 2] + W1[d + 3] * sL[d + 3];
            }
        }
        out[t] = a0;
        out[t + 256] = a1;
    } else {
        int h = t >> 6, i = (t >> 3) & 7, j = t & 7;
        float gb = 0.f;
#pragma unroll
        for (int l = 0; l < 8; ++l) gb += gbu[h * 64 + i * 8 + l] * gbv[h * 64 + l * 8 + j];
        if (i == j) bias_diag[h * 8 + i] = gb;
        sL[t] = fabsf(gb);
        __syncthreads();
        for (int s = 128; s >= 1; s >>= 1) {
            if (t < s) sL[t] += sL[t + s];
            __syncthreads();
        }
        if (t == 0) {
            float gbmean = sL[0] / 256.f;
            reg_out[0] = expf(log_reg[0]) * (0.125f + gbmean * 0.1f);
        }
        if (t < 32) {
            int b = t >> 2, hh = t & 3;
            float a = 0.f;
            for (int d = 0; d < HD; ++d) a += bq[hh * HD + d] * ksum[b * Hh + hh * HD + d];
            bias_q[t] = a;  // [b][h]
        }
    }
}

// ---------------- K5: main pass (no LDS, all weights in registers) ----------------
// grid (250, B), block 256 = 4 waves; wave-per-row.
__global__ __launch_bounds__(256) void k_main(const float* __restrict__ x,
                                              const float* __restrict__ bo,
                                              const float* __restrict__ wqe,
                                              const float* __restrict__ woe,
                                              const float* __restrict__ esum,
                                              const float* __restrict__ fsum,
                                              const float* __restrict__ bias_q,
                                              const float* __restrict__ bias_diag,
                                              float* __restrict__ out) {
    int b = blockIdx.y;
    int t = threadIdx.x;
    int wid = t >> 6, lane = t & 63;

    const float* wqe_b = wqe + (size_t)b * HEADS * Hh;
    const float* woe_b = woe + (size_t)b * HEADS * Hh;
    float4 wqa[HEADS], wqb[HEADS], woa[HEADS], wob[HEADS];
#pragma unroll
    for (int h = 0; h < HEADS; ++h) {
        wqa[h] = *(const float4*)(wqe_b + h * Hh + lane * 4);
        wqb[h] = *(const float4*)(wqe_b + h * Hh + 256 + lane * 4);
        woa[h] = *(const float4*)(woe_b + h * Hh + lane * 4);
        wob[h] = *(const float4*)(woe_b + h * Hh + 256 + lane * 4);
    }
    float4 boa = *(const float4*)(bo + lane * 4);
    float4 bob = *(const float4*)(bo + 256 + lane * 4);

    // quadrant softmax mapping: quadrant q = lane>>4 holds head hq = {0,2,1,3}[q]
    int q = lane >> 4;
    int hq = (q == 0) ? 0 : (q == 1) ? 2 : (q == 2) ? 1 : 3;
    int kk = lane & 7;
    float eV = esum[hq * KB + kk];
    float fV = fsum[hq * KB + kk];
    float bdV = bias_diag[hq * KB + kk];
    float bqV = bias_q[b * HEADS + hq];

    const float inv_sqrt_hd = 0.08838834764831843f;  // 1/sqrt(128)
    int wavesPerB = gridDim.x * 4;
    bool hi32 = (lane & 32) != 0;
    bool hi16 = (lane & 16) != 0;

    for (int n = blockIdx.x * 4 + wid; n < Nn; n += wavesPerB) {
        const float* xr = x + ((size_t)b * Nn + n) * Hh;
        float4 xa = *(const float4*)(xr + lane * 4);
        float4 xb = *(const float4*)(xr + 256 + lane * 4);
        float p[HEADS];
#pragma unroll
        for (int h = 0; h < HEADS; ++h) {
            p[h] = xa.x * wqa[h].x + xa.y * wqa[h].y + xa.z * wqa[h].z + xa.w * wqa[h].w +
                   xb.x * wqb[h].x + xb.y * wqb[h].y + xb.z * wqb[h].z + xb.w * wqb[h].w;
        }
        // folded butterfly: 7 shfl instead of 24.
        // stage 1 (xor 32): lo lanes accumulate heads {0,2}, hi lanes heads {1,3}
        float A  = hi32 ? p[1] : p[0];
        float Bv = hi32 ? p[0] : p[1];
        A += __shfl_xor(Bv, 32, 64);
        float C  = hi32 ? p[3] : p[2];
        float D  = hi32 ? p[2] : p[3];
        C += __shfl_xor(D, 32, 64);
        // stage 2 (xor 16): quadrants get heads {0,2,1,3}
        float Ev = hi16 ? C : A;
        float Fv = hi16 ? A : C;
        Ev += __shfl_xor(Fv, 16, 64);
        // stage 3: full reduce within 16-lane quadrant
        Ev += __shfl_xor(Ev, 1, 64);
        Ev += __shfl_xor(Ev, 2, 64);
        Ev += __shfl_xor(Ev, 4, 64);
        Ev += __shfl_xor(Ev, 8, 64);
        // Ev = full 64-lane dot for head hq, identical across the quadrant

        float sq = (Ev + bqV) * inv_sqrt_hd;
        float sc = eV * sq + bdV;
        float m = sc;
        m = fmaxf(m, __shfl_xor(m, 1, 64));
        m = fmaxf(m, __shfl_xor(m, 2, 64));
        m = fmaxf(m, __shfl_xor(m, 4, 64));
        float e = __expf(sc - m);
        float se = e, sw = e * fV;
        se += __shfl_xor(se, 1, 64); sw += __shfl_xor(sw, 1, 64);
        se += __shfl_xor(se, 2, 64); sw += __shfl_xor(sw, 2, 64);
        se += __shfl_xor(se, 4, 64); sw += __shfl_xor(sw, 4, 64);
        float wv = sw / se;
        float w0 = __shfl(wv, 0, 64);
        float w2 = __shfl(wv, 16, 64);
        float w1 = __shfl(wv, 32, 64);
        float w3 = __shfl(wv, 48, 64);

        float4 oa = boa, ob = bob;
        oa.x += w0 * woa[0].x + w1 * woa[1].x + w2 * woa[2].x + w3 * woa[3].x;
        oa.y += w0 * woa[0].y + w1 * woa[1].y + w2 * woa[2].y + w3 * woa[3].y;
        oa.z += w0 * woa[0].z + w1 * woa[1].z + w2 * woa[2].z + w3 * woa[3].z;
        oa.w += w0 * woa[0].w + w1 * woa[1].w + w2 * woa[2].w + w3 * woa[3].w;
        ob.x += w0 * wob[0].x + w1 * wob[1].x + w2 * wob[2].x + w3 * wob[3].x;
        ob.y += w0 * wob[0].y + w1 * wob[1].y + w2 * wob[2].y + w3 * wob[3].y;
        ob.z += w0 * wob[0].z + w1 * wob[1].z + w2 * wob[2].z + w3 * wob[3].z;
        ob.w += w0 * wob[0].w + w1 * wob[1].w + w2 * wob[2].w + w3 * wob[3].w;

        float* orow = out + ((size_t)b * Nn + n) * Hh;
        *(float4*)(orow + lane * 4) = oa;
        *(float4*)(orow + 256 + lane * 4) = ob;
    }
}

extern "C" void kernel_launch(void* const* d_in, const int* in_sizes, int n_in,
                              void* d_out, int out_size, void* d_ws, size_t ws_size,
                              hipStream_t stream) {
    const float* x       = (const float*)d_in[0];
    const float* Wq      = (const float*)d_in[1];
    const float* bq      = (const float*)d_in[2];
    const float* Wk      = (const float*)d_in[3];
    const float* bk      = (const float*)d_in[4];
    const float* Wv      = (const float*)d_in[5];
    const float* bv      = (const float*)d_in[6];
    const float* E       = (const float*)d_in[7];
    const float* Fp      = (const float*)d_in[8];
    const float* gbu     = (const float*)d_in[9];
    const float* gbv     = (const float*)d_in[10];
    const float* Wo      = (const float*)d_in[11];
    const float* bo      = (const float*)d_in[12];
    const float* log_reg = (const float*)d_in[13];

    float* out = (float*)d_out;
    float* ws = (float*)d_ws;
    float* xs   = ws;  // reuse XS region at offset 0
    float* ksum = ws + KSUM_OFF;
    float* vsum = ws + VSUM_OFF;
    float* wqe  = ws + WQE_OFF;
    float* woe  = ws + WOE_OFF;
    float* esum = ws + ESUM_OFF;
    float* fsum = ws + FSUM_OFF;
    float* bias_q = ws + BQ_OFF;
    float* bias_diag = ws + BD_OFF;
    float* reg_out = out + (size_t)Bsz * Nn * Hh;

    // stage partials in d_out's head region (overwritten by k_main afterwards)
    float* xpart  = out;
    float* efpart = out + (size_t)NPART * Bsz * Hh;

    k_part<<<NPART * Bsz + 64, 256, 0, stream>>>(x, E, Fp, xpart, efpart);
    k_reduce<<<17, 256, 0, stream>>>(xpart, efpart, xs, esum, fsum);
    k_gemv<<<dim3(2, 8), 256, 0, stream>>>(Wk, bk, Wv, bv, xs, ksum, vsum);
    k_eff2<<<65, 256, 0, stream>>>(Wq, Wo, ksum, vsum, wqe, woe,
                                   bq, gbu, gbv, log_reg, bias_q, bias_diag, reg_out);
    k_main<<<dim3(250, Bsz), 256, 0, stream>>>(x, bo, wqe, woe, esum, fsum, bias_q, bias_diag, out);
}